// Round 5
// baseline (200.926 us; speedup 1.0000x reference)
//
#include <hip/hip_runtime.h>

#define BB   128
#define JJ   17
#define YY   96
#define XX   72
#define YX   (YY * XX)        // 6912 floats per (b,j) per channel
#define N4   (YX / 4)         // 1728 float4s per tile (multiple of 64!)
#define NQ   (BB * JJ)        // 2176 tiles
#define NTOT (NQ * YX)        // 15040512 elements per channel
#define NV4  (NQ * N4)        // 3760128 float4s per channel
#define GRID 2048             // exactly the resident capacity (8 blk/CU x 256 CU)
#define STRIDE (GRID * 256)   // 524288 float4s per sweep (multiple of 64)
// 7 full sweeps (3670016) + tail of 90112 float4s (threads with gid < 90112)

typedef float f32x4 __attribute__((ext_vector_type(4)));

// Sum of squared diffs for one float4 pair at float4-index r within a tile.
// yy = r/18 ; xx = (r%18)*4. gt uses trunc-toward-zero (np int32 cast) ==
// truncf for |z| < 2^31. Operand order fl((x+k)-cx) bit-identical to ref.
__device__ __forceinline__ float tile_term(f32x4 lx, f32x4 ly, int r,
                                           float cx, float cy) {
    const int yy = r / 18;                // magic-mul constant divide
    const int xx = (r - yy * 18) * 4;
    const float gy = truncf((float)yy - cy);
    const float xxf = (float)xx;
    float s = 0.0f;
    #pragma unroll
    for (int k = 0; k < 4; ++k) {
        const float gx = truncf((xxf + (float)k) - cx);
        const float dx = lx[k] - gx;
        s = fmaf(dx, dx, s);
        const float dy = ly[k] - gy;
        s = fmaf(dy, dy, s);
    }
    return s;
}

// w^2-weighted term for flat float4 index i. Since N4, STRIDE and the block
// base are all multiples of 64, every wave's indices lie in ONE tile ->
// q and the cord/tw lookups are wave-uniform (L1 broadcast).
// loc tile q is (b=q/17, j=q%17) -> tw[q]; gt's raw-reshape quirk makes the
// cord lookup use (j'=q>>7, b'=q&127) — verified absmax=0 in rounds 0-4.
__device__ __forceinline__ float term_at(const float* __restrict__ cord,
                                         const float* __restrict__ tw,
                                         int i, f32x4 ax, f32x4 ay) {
    const int q = i / N4;                 // magic divide
    const int r = i - q * N4;
    const int jj = q >> 7;
    const int bb = q & 127;
    const float cx = cord[jj * BB + bb];
    const float cy = cord[JJ * BB + jj * BB + bb];
    const float w  = tw[q];
    return (w * w) * tile_term(ax, ay, r, cx, cy);
}

// Stage 1: perfectly balanced flat grid-stride. Grid == resident capacity
// (2048 blocks) so there is NO second dispatch round (the old 2176-block
// layout had a 128-block straggler round, ~94% of the machine idle).
// 2-deep register prefetch keeps 4 float4s/thread in flight — 131 KB/CU,
// far above the ~10 KB BW*latency product, so HBM latency stays hidden
// while VGPR stays <=64 (8 waves/SIMD).
__global__ __launch_bounds__(256, 8) void regloss_partial_kernel(
    const float* __restrict__ loc,    // (2, B, J, Y, X)
    const float* __restrict__ cord,   // (2, J, B)
    const float* __restrict__ tw,     // (B, J, 1)
    float* __restrict__ partial)      // (GRID,) in d_ws
{
    const int tid = threadIdx.x;
    const int gid = blockIdx.x * 256 + tid;

    const f32x4* p0 = (const f32x4*)loc;           // channel x
    const f32x4* p1 = (const f32x4*)(loc + NTOT);  // channel y

    float acc = 0.0f;
    int i = gid;
    f32x4 ax = p0[i], ay = p1[i];
    #pragma unroll
    for (int k = 0; k < 7; ++k) {
        const int inext = i + STRIDE;
        f32x4 bx = {}, by = {};
        if (k < 6 || inext < NV4) {   // k<6 folds to true; k==6 predicated tail
            bx = p0[inext];
            by = p1[inext];
        }
        acc += term_at(cord, tw, i, ax, ay);
        i = inext; ax = bx; ay = by;
    }
    if (i < NV4)                      // tail sweep: threads with gid < 90112
        acc += term_at(cord, tw, i, ax, ay);

    // wave64 shuffle reduction
    #pragma unroll
    for (int off = 32; off > 0; off >>= 1)
        acc += __shfl_down(acc, off, 64);

    __shared__ float wsum[4];
    const int lane = tid & 63;
    const int wave = tid >> 6;
    if (lane == 0) wsum[wave] = acc;
    __syncthreads();

    if (tid == 0)
        partial[blockIdx.x] = wsum[0] + wsum[1] + wsum[2] + wsum[3];
}

// Stage 2: single block folds the 2048 partials, scales, stores the scalar.
// (Do NOT fuse via last-block-done ticket: per-block device-scope fences
// emit buffer_wbl2/buffer_inv on gfx950's non-coherent L2s -> 8x regression,
// measured rounds 2-3.)
__global__ __launch_bounds__(256) void regloss_final_kernel(
    const float* __restrict__ partial, float* __restrict__ out)
{
    float acc = 0.0f;
    for (int i = threadIdx.x; i < GRID; i += 256)
        acc += partial[i];

    #pragma unroll
    for (int off = 32; off > 0; off >>= 1)
        acc += __shfl_down(acc, off, 64);

    __shared__ float wsum[4];
    const int lane = threadIdx.x & 63;
    const int wave = threadIdx.x >> 6;
    if (lane == 0) wsum[wave] = acc;
    __syncthreads();

    if (threadIdx.x == 0) {
        const float s = wsum[0] + wsum[1] + wsum[2] + wsum[3];
        out[0] = s * (0.5f / (float)NTOT);   // 0.5 / (J * B * YX)
    }
}

extern "C" void kernel_launch(void* const* d_in, const int* in_sizes, int n_in,
                              void* d_out, int out_size, void* d_ws, size_t ws_size,
                              hipStream_t stream) {
    const float* loc  = (const float*)d_in[0];   // (2,128,17,96,72) fp32
    const float* cord = (const float*)d_in[1];   // (2,17,128) fp32
    const float* tw   = (const float*)d_in[2];   // (128,17,1) fp32
    float* partial = (float*)d_ws;               // GRID floats, overwritten each call
    float* out = (float*)d_out;

    regloss_partial_kernel<<<GRID, 256, 0, stream>>>(loc, cord, tw, partial);
    regloss_final_kernel<<<1, 256, 0, stream>>>(partial, out);
}

// Round 6
// 178.939 us; speedup vs baseline: 1.1229x; 1.1229x over previous
//
#include <hip/hip_runtime.h>

#define BB   128
#define JJ   17
#define YY   96
#define XX   72
#define YX   (YY * XX)        // 6912 floats per (b,j) per channel
#define N4   (YX / 4)         // 1728 float4s
#define NQ   (BB * JJ)        // 2176 blocks / partials
#define NTOT (NQ * YX)        // 15040512 elements per channel
#define UNI  6                // uniform float4 iters/thread (6*256 = 1536)
#define TAIL (N4 - UNI * 256) // 192 remaining float4s (threads 0..191)

typedef float f32x4 __attribute__((ext_vector_type(4)));

// Sum of squared diffs for one float4 pair at float4-index i within a q-tile.
// yy = (4i)/72 = i/18 ; xx = (i%18)*4.
// gt uses trunc-toward-zero (np int32 cast) == truncf for |z| < 2^31.
// Operand order fl((x+k) - cx) kept bit-identical to the reference.
__device__ __forceinline__ float tile_term(f32x4 lx, f32x4 ly, int i,
                                           float cx, float cy) {
    const int yy = i / 18;                // magic-mul constant divide
    const int xx = (i - yy * 18) * 4;
    const float gy = truncf((float)yy - cy);
    const float xxf = (float)xx;
    float s = 0.0f;
    #pragma unroll
    for (int k = 0; k < 4; ++k) {
        const float gx = truncf((xxf + (float)k) - cx);  // (float)(xx+k) exact
        const float dx = lx[k] - gx;
        s = fmaf(dx, dx, s);
        const float dy = ly[k] - gy;
        s = fmaf(dy, dy, s);
    }
    return s;
}

// Stage 1: one block per q = b*J + j. Measured-best geometry (175.0 us total).
// Experiment ledger (do not re-try):
//  - half-tile 4352-block variant: 179.9 us (null, noise)
//  - last-block-done fusion: 346-358 us. Per-block __threadfence + agent-scope
//    atomic emits buffer_wbl2/buffer_inv on gfx950's NON-coherent per-XCD L2s
//    -> TCC stalled 2176x. Never fuse cross-block reductions this way here.
//  - balanced 2048-block grid-stride + __launch_bounds__(256,8): 200.9 us.
//    VGPR capped at 32 -> prefetch payload spilled to scratch (WRITE_SIZE
//    ballooned 0.1 -> 76 MB). Min-waves bounds below payload size = spills.
__global__ __launch_bounds__(256) void regloss_partial_kernel(
    const float* __restrict__ loc,    // (2, B, J, Y, X)
    const float* __restrict__ cord,   // (2, J, B)
    const float* __restrict__ tw,     // (B, J, 1)
    float* __restrict__ partial)      // (NQ,) in d_ws
{
    const int tid = threadIdx.x;
    const int q  = blockIdx.x;
    const int jj = q >> 7;            // q / 128
    const int bb = q & 127;           // q % 128

    const float cx = cord[jj * BB + bb];
    const float cy = cord[JJ * BB + jj * BB + bb];
    const float w  = tw[q];

    const f32x4* p0 = (const f32x4*)(loc + (size_t)q * YX);
    const f32x4* p1 = (const f32x4*)(loc + (size_t)NTOT + (size_t)q * YX);

    f32x4 lx[UNI + 1], ly[UNI + 1];
    #pragma unroll
    for (int k = 0; k < UNI; ++k) lx[k] = p0[tid + 256 * k];
    #pragma unroll
    for (int k = 0; k < UNI; ++k) ly[k] = p1[tid + 256 * k];
    const bool has_tail = tid < TAIL;
    if (has_tail) {
        lx[UNI] = p0[UNI * 256 + tid];
        ly[UNI] = p1[UNI * 256 + tid];
    }

    float acc = 0.0f;
    #pragma unroll
    for (int k = 0; k < UNI; ++k)
        acc += tile_term(lx[k], ly[k], tid + 256 * k, cx, cy);
    if (has_tail)
        acc += tile_term(lx[UNI], ly[UNI], UNI * 256 + tid, cx, cy);

    // wave64 shuffle reduction
    #pragma unroll
    for (int off = 32; off > 0; off >>= 1)
        acc += __shfl_down(acc, off, 64);

    __shared__ float wsum[4];
    const int lane = tid & 63;
    const int wave = tid >> 6;
    if (lane == 0) wsum[wave] = acc;
    __syncthreads();

    if (tid == 0)   // w is uniform per block: apply w^2 once here
        partial[q] = (w * w) * (wsum[0] + wsum[1] + wsum[2] + wsum[3]);
}

// Stage 2: single block folds the 2176 partials, scales, stores the scalar.
__global__ __launch_bounds__(256) void regloss_final_kernel(
    const float* __restrict__ partial, float* __restrict__ out)
{
    float acc = 0.0f;
    for (int i = threadIdx.x; i < NQ; i += 256)
        acc += partial[i];

    #pragma unroll
    for (int off = 32; off > 0; off >>= 1)
        acc += __shfl_down(acc, off, 64);

    __shared__ float wsum[4];
    const int lane = threadIdx.x & 63;
    const int wave = threadIdx.x >> 6;
    if (lane == 0) wsum[wave] = acc;
    __syncthreads();

    if (threadIdx.x == 0) {
        const float s = wsum[0] + wsum[1] + wsum[2] + wsum[3];
        out[0] = s * (0.5f / (float)NTOT);   // 0.5 / (J * B * YX)
    }
}

extern "C" void kernel_launch(void* const* d_in, const int* in_sizes, int n_in,
                              void* d_out, int out_size, void* d_ws, size_t ws_size,
                              hipStream_t stream) {
    const float* loc  = (const float*)d_in[0];   // (2,128,17,96,72) fp32
    const float* cord = (const float*)d_in[1];   // (2,17,128) fp32
    const float* tw   = (const float*)d_in[2];   // (128,17,1) fp32
    float* partial = (float*)d_ws;               // NQ floats, overwritten each call
    float* out = (float*)d_out;

    regloss_partial_kernel<<<NQ, 256, 0, stream>>>(loc, cord, tw, partial);
    regloss_final_kernel<<<1, 256, 0, stream>>>(partial, out);
}